// Round 2
// baseline (237.877 us; speedup 1.0000x reference)
//
#include <hip/hip_runtime.h>

// Attention fwd, B=16 S=4096 D=64, fp32 in/out, bf16 MFMA flash kernel. R2:
// 512-thr blocks (8 waves): waves wk=0/1 split key tiles (even/odd) over a
// shared 64-key double-buffered K/V stage -> 16 waves/CU. P C->A relayout via
// shfl_xor(32) instead of LDS round-trip. Scale folded into Q fragments.

#define S_LEN 4096
#define HD    64
#define NSTG  64    // stages of 64 keys
#define KSTR  72    // Kld row stride (elems): 144B, conflict-free b128 reads
#define VSTR  72    // Vt  row stride (elems)

typedef __bf16 bf16x8 __attribute__((ext_vector_type(8)));
typedef float  f32x16 __attribute__((ext_vector_type(16)));

// round-half-up fp32->bf16, pack two into a dword
__device__ __forceinline__ unsigned int pack_bf16(float x, float y) {
  unsigned int ux = __builtin_bit_cast(unsigned int, x) + 0x8000u;
  unsigned int uy = __builtin_bit_cast(unsigned int, y) + 0x8000u;
  return (ux >> 16) | (uy & 0xffff0000u);
}
__device__ __forceinline__ __bf16 to_bf16(float x) {
  unsigned short us =
      (unsigned short)((__builtin_bit_cast(unsigned int, x) + 0x8000u) >> 16);
  return __builtin_bit_cast(__bf16, us);
}

__global__ __launch_bounds__(512, 4) void attn_fwd(
    const float* __restrict__ Qg, const float* __restrict__ Kg,
    const float* __restrict__ Vg, float* __restrict__ Og) {
  const int bid = blockIdx.x;
  const int batch = ((bid & 7) << 1) | (bid >> 8);  // XCD-aware swizzle
  const int q0    = ((bid >> 3) & 31) << 7;         // 128 q rows per block

  const int tid  = threadIdx.x;
  const int wave = tid >> 6;
  const int lane = tid & 63;
  const int l32  = lane & 31;
  const int h    = lane >> 5;   // 0/1
  const int wq   = wave & 3;    // q sub-tile (32 rows)
  const int wk   = wave >> 2;   // key parity group
  const int ko   = wk << 5;     // key offset within 64-key stage

  const size_t boff = (size_t)batch * (S_LEN * HD);
  const float* __restrict__ Qb = Qg + boff;
  const float* __restrict__ Kb = Kg + boff;
  const float* __restrict__ Vb = Vg + boff;
  float* __restrict__ Ob = Og + boff;

  // Staging LDS (reused as epilogue exchange buffer):
  //   Kld: [2][64 keys][KSTR]  18432 B   (bf16, [key][d])
  //   Vt : [2][64 d  ][VSTR]   18432 B   (bf16, [d][key])
  //   exch (epilogue): 4 * 33 * 64 floats = 33792 B  (aliased)
  __shared__ __align__(16) unsigned char smraw[36864];
  __bf16* Kp = (__bf16*)smraw;
  __bf16* Vp = Kp + 2 * 64 * KSTR;
  float*  exch = (float*)smraw;

  // ---- persistent Q fragments (B-operand: n=l32->q, k=h*8+j->d), scale folded
  const float cs = 0.18033688011112042f;  // (1/sqrt(64)) * log2(e)
  const int qrow = q0 + (wq << 5) + l32;
  bf16x8 qf[4];
#pragma unroll
  for (int dc = 0; dc < 4; ++dc) {
    const float* p = Qb + qrow * HD + dc * 16 + h * 8;
    float4 a = *(const float4*)p;
    float4 b = *(const float4*)(p + 4);
    uint4 uu;
    uu.x = pack_bf16(a.x * cs, a.y * cs);
    uu.y = pack_bf16(a.z * cs, a.w * cs);
    uu.z = pack_bf16(b.x * cs, b.y * cs);
    uu.w = pack_bf16(b.z * cs, b.w * cs);
    qf[dc] = __builtin_bit_cast(bf16x8, uu);
  }

  // ---- stage keys [0,64) into buffer 0 ----
#pragma unroll
  for (int k = 0; k < 4; ++k) {
    const int e = 2 * (tid + (k << 9));            // K: flat fp32, coalesced
    float2 kv = *(const float2*)(Kb + e);
    *(unsigned int*)&Kp[(e >> 6) * KSTR + (e & 63)] = pack_bf16(kv.x, kv.y);
    const int idx = tid + (k << 9);                // V: key-major -> 2-way LDS
    const int key = idx & 63, dp = idx >> 6;
    float2 vv = *(const float2*)(Vb + key * HD + 2 * dp);
    Vp[(2 * dp) * VSTR + key]     = to_bf16(vv.x);
    Vp[(2 * dp + 1) * VSTR + key] = to_bf16(vv.y);
  }

  f32x16 acc0{};   // out cols d=0..31 (C: col=l32->q ... wait, col=d here)
  f32x16 acc1{};   // out cols d=32..63
  float rowsum = 0.0f;

  for (int it = 0; it < NSTG; ++it) {
    __syncthreads();
    const int cb = it & 1;
    const bool pre = (it + 1 < NSTG);

    // prefetch next 64-key stage into regs (consumed after compute)
    float2 kpre[4], vpre[4];
    if (pre) {
      const float* ksrc = Kb + (it + 1) * (64 * HD);
      const float* vsrc = Vb + (it + 1) * (64 * HD);
#pragma unroll
      for (int k = 0; k < 4; ++k) {
        const int e = 2 * (tid + (k << 9));
        kpre[k] = *(const float2*)(ksrc + e);
        const int idx = tid + (k << 9);
        const int key = idx & 63, dp = idx >> 6;
        vpre[k] = *(const float2*)(vsrc + key * HD + 2 * dp);
      }
    }

    // ---- S^T = K*Q^T : A=K (m=key), B=Q^T (n=q) ----
    f32x16 s{};
#pragma unroll
    for (int dc = 0; dc < 4; ++dc) {
      bf16x8 ka =
          *(const bf16x8*)&Kp[cb * (64 * KSTR) + (ko + l32) * KSTR + dc * 16 + h * 8];
      s = __builtin_amdgcn_mfma_f32_32x32x16_bf16(ka, qf[dc], s, 0, 0, 0);
    }

    // ---- p = exp2(s) (scale pre-folded); pack pairs; reg r -> key (r&3)+8*(r>>2)+4h
    unsigned int w[8];
#pragma unroll
    for (int j = 0; j < 8; ++j) {
      float p0 = __builtin_amdgcn_exp2f(s[2 * j]);
      float p1 = __builtin_amdgcn_exp2f(s[2 * j + 1]);
      rowsum += p0 + p1;
      w[j] = pack_bf16(p0, p1);
    }

    // ---- C->A relayout: partner lane is l^32 (same q) ----
    unsigned int y[8];
#pragma unroll
    for (int j = 0; j < 8; ++j)
      y[j] = (unsigned int)__shfl_xor((int)w[j], 32, 64);

    uint4 pa0 = {h ? y[2] : w[0], h ? y[3] : w[1], h ? w[2] : y[0], h ? w[3] : y[1]};
    uint4 pa1 = {h ? y[6] : w[4], h ? y[7] : w[5], h ? w[6] : y[4], h ? w[7] : y[5]};

    // ---- O += P*V : A=P (m=q), B=V (k=key, n=d) via Vt rows ----
#pragma unroll
    for (int kc = 0; kc < 2; ++kc) {
      bf16x8 pa = __builtin_bit_cast(bf16x8, kc ? pa1 : pa0);
      const __bf16* vbase = &Vp[cb * (HD * VSTR) + ko + kc * 16 + h * 8];
      bf16x8 vb0 = *(const bf16x8*)&vbase[l32 * VSTR];
      bf16x8 vb1 = *(const bf16x8*)&vbase[(32 + l32) * VSTR];
      acc0 = __builtin_amdgcn_mfma_f32_32x32x16_bf16(pa, vb0, acc0, 0, 0, 0);
      acc1 = __builtin_amdgcn_mfma_f32_32x32x16_bf16(pa, vb1, acc1, 0, 0, 0);
    }

    // ---- convert+write prefetched stage into the other buffer ----
    if (pre) {
      const int nb = cb ^ 1;
#pragma unroll
      for (int k = 0; k < 4; ++k) {
        const int e = 2 * (tid + (k << 9));
        *(unsigned int*)&Kp[nb * (64 * KSTR) + (e >> 6) * KSTR + (e & 63)] =
            pack_bf16(kpre[k].x, kpre[k].y);
        const int idx = tid + (k << 9);
        const int key = idx & 63, dp = idx >> 6;
        Vp[nb * (HD * VSTR) + (2 * dp) * VSTR + key]     = to_bf16(vpre[k].x);
        Vp[nb * (HD * VSTR) + (2 * dp + 1) * VSTR + key] = to_bf16(vpre[k].y);
      }
    }
  }

  // ---- epilogue: combine wk=0 + wk=1 partials via LDS, normalize, store ----
  rowsum += __shfl_xor(rowsum, 32, 64);   // both h halves now have wave rowsum
  __syncthreads();                        // staging LDS dead; reuse as exch
  const int ebase = wq * (33 * 64);
  if (wk == 1) {
#pragma unroll
    for (int r = 0; r < 16; ++r) {
      exch[ebase + r * 64 + lane]        = acc0[r];
      exch[ebase + (16 + r) * 64 + lane] = acc1[r];
    }
    exch[ebase + 32 * 64 + lane] = rowsum;
  }
  __syncthreads();
  if (wk == 0) {
#pragma unroll
    for (int r = 0; r < 16; ++r) {
      acc0[r] += exch[ebase + r * 64 + lane];
      acc1[r] += exch[ebase + (16 + r) * 64 + lane];
    }
    const float rs  = rowsum + exch[ebase + 32 * 64 + lane];
    const float inv = 1.0f / rs;
#pragma unroll
    for (int r = 0; r < 16; ++r) {
      const int qrl  = (r & 3) + ((r >> 2) << 3) + (h << 2);  // C row -> q
      const float iv = __shfl(inv, qrl, 64);                  // inv lives at lane q
      float* op = Ob + (size_t)(q0 + (wq << 5) + qrl) * HD + l32;
      op[0]  = acc0[r] * iv;
      op[32] = acc1[r] * iv;
    }
  }
}

extern "C" void kernel_launch(void* const* d_in, const int* in_sizes, int n_in,
                              void* d_out, int out_size, void* d_ws, size_t ws_size,
                              hipStream_t stream) {
  const float* Q = (const float*)d_in[0];
  const float* K = (const float*)d_in[1];
  const float* V = (const float*)d_in[2];
  float* O = (float*)d_out;
  attn_fwd<<<dim3(512), dim3(512), 0, stream>>>(Q, K, V, O);
}

// Round 4
// 176.935 us; speedup vs baseline: 1.3444x; 1.3444x over previous
//
#include <hip/hip_runtime.h>
#include <cstdint>

// Attention fwd B=16 S=4096 D=64 fp32, bf16-MFMA flash. R4 = R3 + fix:
// aV[] swizzled group index was missing the wk*4 key-offset term (wk=1 waves
// read V keys 0-31 instead of 32-63). Structure unchanged: prepass converts
// K->bf16 and V->V^T bf16 (swizzled tiles) in d_ws; main loop stages via
// global_load_lds dwordx4; P relayout via v_permlane32_swap_b32; rowsum via
// ones-column MFMA.

#define S_LEN 4096
#define HD    64
#define NSTG  64     // stages of 64 keys

typedef __bf16 bf16x8 __attribute__((ext_vector_type(8)));
typedef float  f32x16 __attribute__((ext_vector_type(16)));

__device__ __forceinline__ unsigned pack_bf16(float x, float y) {
  unsigned ux = __builtin_bit_cast(unsigned, x) + 0x8000u;
  unsigned uy = __builtin_bit_cast(unsigned, y) + 0x8000u;
  return (ux >> 16) | (uy & 0xffff0000u);
}
__device__ __forceinline__ unsigned cvt_pk(float lo, float hi) {
  unsigned d;
  asm("v_cvt_pk_bf16_f32 %0, %1, %2" : "=v"(d) : "v"(lo), "v"(hi));
  return d;
}
#define AS1 __attribute__((address_space(1)))
#define AS3 __attribute__((address_space(3)))
__device__ __forceinline__ void gld16(const void* g, void* l) {
  __builtin_amdgcn_global_load_lds((const AS1 void*)(uintptr_t)g,
                                   (AS3 void*)(uintptr_t)l, 16, 0, 0);
}

// ---- prepass 1: K fp32 -> bf16, 16B groups xor-swizzled by (row&7) ----
__global__ __launch_bounds__(256) void conv_k(const float* __restrict__ K,
                                              uint16_t* __restrict__ Kw) {
  const int t   = blockIdx.x * 256 + threadIdx.x;  // one 16B dst group each
  const int row = t >> 3;                          // b*4096 + key
  const int gs  = t & 7;
  const float* p = K + (size_t)row * 64 + ((gs ^ (row & 7)) << 3);
  float4 a = *(const float4*)p;
  float4 b = *(const float4*)(p + 4);
  uint4 o = {pack_bf16(a.x, a.y), pack_bf16(a.z, a.w),
             pack_bf16(b.x, b.y), pack_bf16(b.z, b.w)};
  *(uint4*)(Kw + (size_t)t * 8) = o;
}

// ---- prepass 2: V -> V^T bf16 per (batch,stage) tile, swizzled by (d&7) ----
__global__ __launch_bounds__(256) void conv_vt(const float* __restrict__ V,
                                               uint16_t* __restrict__ Vw) {
  const int b = blockIdx.x >> 6, st = blockIdx.x & 63;
  const int t = threadIdx.x;
  __shared__ uint16_t Vb[64 * 72];
  const float* src = V + ((size_t)b * S_LEN + st * 64) * 64;
  const int k = t >> 2, dq = (t & 3) * 16;
  const float* p = src + k * 64 + dq;
  float4 x0 = *(const float4*)p,       x1 = *(const float4*)(p + 4);
  float4 x2 = *(const float4*)(p + 8), x3 = *(const float4*)(p + 12);
  unsigned* dst = (unsigned*)&Vb[k * 72 + dq];
  dst[0] = pack_bf16(x0.x, x0.y); dst[1] = pack_bf16(x0.z, x0.w);
  dst[2] = pack_bf16(x1.x, x1.y); dst[3] = pack_bf16(x1.z, x1.w);
  dst[4] = pack_bf16(x2.x, x2.y); dst[5] = pack_bf16(x2.z, x2.w);
  dst[6] = pack_bf16(x3.x, x3.y); dst[7] = pack_bf16(x3.z, x3.w);
  __syncthreads();
  uint16_t* out = Vw + ((size_t)b * 64 + st) * 4096;
#pragma unroll
  for (int j = 0; j < 2; ++j) {
    const int gi = t + j * 256;              // 512 groups: d=gi>>3, gs=gi&7
    const int d = gi >> 3, gs = gi & 7;
    const int k0 = (gs ^ (d & 7)) << 3;
    unsigned v0 = Vb[(k0 + 0) * 72 + d], v1 = Vb[(k0 + 1) * 72 + d];
    unsigned v2 = Vb[(k0 + 2) * 72 + d], v3 = Vb[(k0 + 3) * 72 + d];
    unsigned v4 = Vb[(k0 + 4) * 72 + d], v5 = Vb[(k0 + 5) * 72 + d];
    unsigned v6 = Vb[(k0 + 6) * 72 + d], v7 = Vb[(k0 + 7) * 72 + d];
    uint4 o = {v0 | (v1 << 16), v2 | (v3 << 16), v4 | (v5 << 16), v6 | (v7 << 16)};
    *(uint4*)(out + (size_t)gi * 8) = o;
  }
}

// ---- main: 1024 blocks x 256 thr; 64 q rows/block; wq=wave&1, wk=wave>>1 ----
__global__ __launch_bounds__(256, 4) void attn_fwd(
    const float* __restrict__ Qg, float* __restrict__ Og,
    const uint16_t* __restrict__ Kw, const uint16_t* __restrict__ Vw) {
  const int bid   = blockIdx.x;
  const int batch = ((bid & 7) << 1) | (bid >> 9);  // 2 batches per XCD
  const int qt    = (bid >> 3) & 63;

  const int tid = threadIdx.x, wave = tid >> 6, lane = tid & 63;
  const int l32 = lane & 31, h = lane >> 5;
  const int wq = wave & 1, wk = wave >> 1;

  // [K0 8K][K1 8K][V0 8K][V1 8K]; epilogue exch aliases from offset 0
  __shared__ __align__(16) unsigned char sm[32768];

  const uint16_t* Kb  = Kw + (size_t)batch * (S_LEN * HD);
  const uint16_t* Vtb = Vw + (size_t)batch * (S_LEN * HD);

  // Q fragments (B-operand: n=l32->q, k=h*8+j->d), softmax scale folded
  const float cs = 0.18033688011112042f;  // (1/sqrt(64))*log2(e)
  const int qrow = qt * 64 + wq * 32 + l32;
  const float* qp = Qg + ((size_t)batch * S_LEN + qrow) * 64;
  bf16x8 qf[4];
#pragma unroll
  for (int dc = 0; dc < 4; ++dc) {
    const float* p = qp + dc * 16 + h * 8;
    float4 a = *(const float4*)p;
    float4 b = *(const float4*)(p + 4);
    uint4 uu = {pack_bf16(a.x * cs, a.y * cs), pack_bf16(a.z * cs, a.w * cs),
                pack_bf16(b.x * cs, b.y * cs), pack_bf16(b.z * cs, b.w * cs)};
    qf[dc] = __builtin_bit_cast(bf16x8, uu);
  }

  // loop-invariant LDS byte offsets (swizzled group addressing)
  const int sw = l32 & 7;
  int aK[4], aV[4];
#pragma unroll
  for (int dc = 0; dc < 4; ++dc)
    aK[dc] = (wk * 32 + l32) * 128 + (((dc * 2 + h) ^ sw) << 4);
#pragma unroll
  for (int kc = 0; kc < 2; ++kc) {
    // keys wk*32 + kc*16 + h*8 .. +8 at d-row l32 (vb0) / 32+l32 (vb1)
    aV[kc * 2 + 0] = 16384 + l32 * 128 + (((wk * 4 + kc * 2 + h) ^ sw) << 4);
    aV[kc * 2 + 1] = 16384 + (32 + l32) * 128 + (((wk * 4 + kc * 2 + h) ^ sw) << 4);
  }

  // DMA one 64-key stage (8KB K + 8KB Vt) into buffer nb; 4 instrs/wave
  auto stage = [&](int nxt, int nb) {
    const uint16_t* ks = Kb + (size_t)nxt * 4096 + wave * 1024 + lane * 8;
    const uint16_t* vs = Vtb + (size_t)nxt * 4096 + wave * 1024 + lane * 8;
    char* kd = (char*)sm + nb * 8192 + wave * 2048;
    char* vd = (char*)sm + 16384 + nb * 8192 + wave * 2048;
    gld16(ks, kd);
    gld16(ks + 512, kd + 1024);
    gld16(vs, vd);
    gld16(vs + 512, vd + 1024);
  };
  stage(0, 0);

  f32x16 acc0{}, acc1{}, rs{};
  const unsigned one2 = 0x3f803f80u;
  uint4 ob = {one2, one2, one2, one2};
  const bf16x8 bones = __builtin_bit_cast(bf16x8, ob);

  auto body = [&](int s, int cb) {
    __syncthreads();               // buffer cb ready; buffer cb^1 free
    if (s + 1 < NSTG) stage(s + 1, cb ^ 1);
    const char* smc = (const char*)sm;
    // S^T = K*Q^T
    f32x16 sc{};
#pragma unroll
    for (int dc = 0; dc < 4; ++dc) {
      bf16x8 ka = *(const bf16x8*)(smc + cb * 8192 + aK[dc]);
      sc = __builtin_amdgcn_mfma_f32_32x32x16_bf16(ka, qf[dc], sc, 0, 0, 0);
    }
    // p = exp2(s) (scale folded); pack pairs (keys 2j,2j+1 within group)
    unsigned w[8];
#pragma unroll
    for (int j = 0; j < 8; ++j) {
      float p0 = __builtin_amdgcn_exp2f(sc[2 * j]);
      float p1 = __builtin_amdgcn_exp2f(sc[2 * j + 1]);
      w[j] = cvt_pk(p0, p1);
    }
    // C->A relayout: one permlane32_swap yields two A dwords
    asm("v_permlane32_swap_b32 %0, %1" : "+v"(w[0]), "+v"(w[2]));
    asm("v_permlane32_swap_b32 %0, %1" : "+v"(w[1]), "+v"(w[3]));
    asm("v_permlane32_swap_b32 %0, %1" : "+v"(w[4]), "+v"(w[6]));
    asm("v_permlane32_swap_b32 %0, %1" : "+v"(w[5]), "+v"(w[7]));
    uint4 u0 = {w[0], w[1], w[2], w[3]};
    uint4 u1 = {w[4], w[5], w[6], w[7]};
    bf16x8 pa0 = __builtin_bit_cast(bf16x8, u0);   // keys 0..15 of wave's 32
    bf16x8 pa1 = __builtin_bit_cast(bf16x8, u1);   // keys 16..31
    // O += P*V ; rowsum += P*1 (ones-column MFMA)
    bf16x8 v00 = *(const bf16x8*)(smc + cb * 8192 + aV[0]);
    bf16x8 v01 = *(const bf16x8*)(smc + cb * 8192 + aV[1]);
    bf16x8 v10 = *(const bf16x8*)(smc + cb * 8192 + aV[2]);
    bf16x8 v11 = *(const bf16x8*)(smc + cb * 8192 + aV[3]);
    acc0 = __builtin_amdgcn_mfma_f32_32x32x16_bf16(pa0, v00, acc0, 0, 0, 0);
    acc1 = __builtin_amdgcn_mfma_f32_32x32x16_bf16(pa0, v01, acc1, 0, 0, 0);
    rs   = __builtin_amdgcn_mfma_f32_32x32x16_bf16(pa0, bones, rs, 0, 0, 0);
    acc0 = __builtin_amdgcn_mfma_f32_32x32x16_bf16(pa1, v10, acc0, 0, 0, 0);
    acc1 = __builtin_amdgcn_mfma_f32_32x32x16_bf16(pa1, v11, acc1, 0, 0, 0);
    rs   = __builtin_amdgcn_mfma_f32_32x32x16_bf16(pa1, bones, rs, 0, 0, 0);
  };
  for (int it = 0; it < NSTG; it += 2) { body(it, 0); body(it + 1, 1); }

  // ---- epilogue: combine wk halves via LDS; per-register normalize ----
  __syncthreads();
  float* exch = (float*)sm;
  const int ebase = wq * (48 * 64);
  if (wk == 1) {
#pragma unroll
    for (int r = 0; r < 16; ++r) {
      exch[ebase + r * 64 + lane]        = acc0[r];
      exch[ebase + (16 + r) * 64 + lane] = acc1[r];
      exch[ebase + (32 + r) * 64 + lane] = rs[r];
    }
  }
  __syncthreads();
  if (wk == 0) {
    float* Ob = Og + ((size_t)batch * S_LEN + qt * 64 + wq * 32) * 64;
#pragma unroll
    for (int r = 0; r < 16; ++r) {
      float a0 = acc0[r] + exch[ebase + r * 64 + lane];
      float a1 = acc1[r] + exch[ebase + (16 + r) * 64 + lane];
      float rt = rs[r]   + exch[ebase + (32 + r) * 64 + lane];
      float iv = __builtin_amdgcn_rcpf(rt);
      const int qrl = (r & 3) + ((r >> 2) << 3) + (h << 2);  // C row -> q
      float* op = Ob + (size_t)qrl * 64 + l32;
      op[0]  = a0 * iv;
      op[32] = a1 * iv;
    }
  }
}

extern "C" void kernel_launch(void* const* d_in, const int* in_sizes, int n_in,
                              void* d_out, int out_size, void* d_ws, size_t ws_size,
                              hipStream_t stream) {
  const float* Q = (const float*)d_in[0];
  const float* K = (const float*)d_in[1];
  const float* V = (const float*)d_in[2];
  float* O = (float*)d_out;
  uint16_t* Kw = (uint16_t*)d_ws;
  uint16_t* Vw = Kw + (size_t)16 * S_LEN * HD;   // 8.39 MB each, 16.8 MB total
  conv_k<<<dim3(2048), dim3(256), 0, stream>>>(K, Kw);
  conv_vt<<<dim3(1024), dim3(256), 0, stream>>>(V, Vw);
  attn_fwd<<<dim3(1024), dim3(256), 0, stream>>>(Q, O, Kw, Vw);
}

// Round 5
// 162.095 us; speedup vs baseline: 1.4675x; 1.0915x over previous
//
#include <hip/hip_runtime.h>
#include <cstdint>

// Attention fwd B=16 S=4096 D=64 fp32, bf16-MFMA flash. R5:
// - 2 q-tiles per wave (64 q rows): 16 MFMA per barrier sharing the same K/V
//   LDS reads; tile chains interleave for intra-wave ILP. Grid 512.
// - rowsum in VALU (16 adds/tile) instead of ones-MFMA.
// - prepasses fused into one dispatch (blockIdx-ranged).

#define S_LEN 4096
#define HD    64
#define NSTG  64     // stages of 64 keys

typedef __bf16 bf16x8 __attribute__((ext_vector_type(8)));
typedef float  f32x16 __attribute__((ext_vector_type(16)));

__device__ __forceinline__ unsigned pack_bf16(float x, float y) {
  unsigned ux = __builtin_bit_cast(unsigned, x) + 0x8000u;
  unsigned uy = __builtin_bit_cast(unsigned, y) + 0x8000u;
  return (ux >> 16) | (uy & 0xffff0000u);
}
__device__ __forceinline__ unsigned cvt_pk(float lo, float hi) {
  unsigned d;
  asm("v_cvt_pk_bf16_f32 %0, %1, %2" : "=v"(d) : "v"(lo), "v"(hi));
  return d;
}
#define AS1 __attribute__((address_space(1)))
#define AS3 __attribute__((address_space(3)))
__device__ __forceinline__ void gld16(const void* g, void* l) {
  __builtin_amdgcn_global_load_lds((const AS1 void*)(uintptr_t)g,
                                   (AS3 void*)(uintptr_t)l, 16, 0, 0);
}

// ---- fused prepass: bid<2048 -> K bf16 swizzled; bid>=2048 -> V^T bf16 ----
__global__ __launch_bounds__(256) void prep(const float* __restrict__ K,
                                            const float* __restrict__ V,
                                            uint16_t* __restrict__ Kw,
                                            uint16_t* __restrict__ Vw) {
  if (blockIdx.x < 2048) {
    const int t   = blockIdx.x * 256 + threadIdx.x;  // one 16B dst group each
    const int row = t >> 3;                          // b*4096 + key
    const int gs  = t & 7;
    const float* p = K + (size_t)row * 64 + ((gs ^ (row & 7)) << 3);
    float4 a = *(const float4*)p;
    float4 b = *(const float4*)(p + 4);
    uint4 o = {pack_bf16(a.x, a.y), pack_bf16(a.z, a.w),
               pack_bf16(b.x, b.y), pack_bf16(b.z, b.w)};
    *(uint4*)(Kw + (size_t)t * 8) = o;
    return;
  }
  const int blk = blockIdx.x - 2048;
  const int b = blk >> 6, st = blk & 63;
  const int t = threadIdx.x;
  __shared__ uint16_t Vb[64 * 72];
  const float* src = V + ((size_t)b * S_LEN + st * 64) * 64;
  const int k = t >> 2, dq = (t & 3) * 16;
  const float* p = src + k * 64 + dq;
  float4 x0 = *(const float4*)p,       x1 = *(const float4*)(p + 4);
  float4 x2 = *(const float4*)(p + 8), x3 = *(const float4*)(p + 12);
  unsigned* dst = (unsigned*)&Vb[k * 72 + dq];
  dst[0] = pack_bf16(x0.x, x0.y); dst[1] = pack_bf16(x0.z, x0.w);
  dst[2] = pack_bf16(x1.x, x1.y); dst[3] = pack_bf16(x1.z, x1.w);
  dst[4] = pack_bf16(x2.x, x2.y); dst[5] = pack_bf16(x2.z, x2.w);
  dst[6] = pack_bf16(x3.x, x3.y); dst[7] = pack_bf16(x3.z, x3.w);
  __syncthreads();
  uint16_t* out = Vw + ((size_t)b * 64 + st) * 4096;
#pragma unroll
  for (int j = 0; j < 2; ++j) {
    const int gi = t + j * 256;              // 512 groups: d=gi>>3, gs=gi&7
    const int d = gi >> 3, gs = gi & 7;
    const int k0 = (gs ^ (d & 7)) << 3;
    unsigned v0 = Vb[(k0 + 0) * 72 + d], v1 = Vb[(k0 + 1) * 72 + d];
    unsigned v2 = Vb[(k0 + 2) * 72 + d], v3 = Vb[(k0 + 3) * 72 + d];
    unsigned v4 = Vb[(k0 + 4) * 72 + d], v5 = Vb[(k0 + 5) * 72 + d];
    unsigned v6 = Vb[(k0 + 6) * 72 + d], v7 = Vb[(k0 + 7) * 72 + d];
    uint4 o = {v0 | (v1 << 16), v2 | (v3 << 16), v4 | (v5 << 16), v6 | (v7 << 16)};
    *(uint4*)(out + (size_t)gi * 8) = o;
  }
}

// ---- main: 512 blocks x 256 thr; 128 q rows/block; wave: 2 q-tiles ----
__global__ __launch_bounds__(256, 2) void attn_fwd(
    const float* __restrict__ Qg, float* __restrict__ Og,
    const uint16_t* __restrict__ Kw, const uint16_t* __restrict__ Vw) {
  const int bid   = blockIdx.x;
  const int batch = ((bid & 7) << 1) | (bid >> 8);  // 2 batches per XCD
  const int q0    = ((bid >> 3) & 31) << 7;         // 128 q rows per block

  const int tid = threadIdx.x, wave = tid >> 6, lane = tid & 63;
  const int l32 = lane & 31, h = lane >> 5;
  const int wq = wave & 1, wk = wave >> 1;

  // [K0 8K][K1 8K][V0 8K][V1 8K]; epilogue exch aliases from offset 0
  __shared__ __align__(16) unsigned char sm[32768];

  const uint16_t* Kb  = Kw + (size_t)batch * (S_LEN * HD);
  const uint16_t* Vtb = Vw + (size_t)batch * (S_LEN * HD);

  // Q fragments, 2 tiles (B-operand: n=l32->q, k=h*8+j->d), scale folded
  const float cs = 0.18033688011112042f;  // (1/sqrt(64))*log2(e)
  bf16x8 qf[2][4];
#pragma unroll
  for (int t = 0; t < 2; ++t) {
    const int qrow = q0 + t * 64 + wq * 32 + l32;
    const float* qp = Qg + ((size_t)batch * S_LEN + qrow) * 64;
#pragma unroll
    for (int dc = 0; dc < 4; ++dc) {
      const float* p = qp + dc * 16 + h * 8;
      float4 a = *(const float4*)p;
      float4 b = *(const float4*)(p + 4);
      uint4 uu = {pack_bf16(a.x * cs, a.y * cs), pack_bf16(a.z * cs, a.w * cs),
                  pack_bf16(b.x * cs, b.y * cs), pack_bf16(b.z * cs, b.w * cs)};
      qf[t][dc] = __builtin_bit_cast(bf16x8, uu);
    }
  }

  // loop-invariant LDS byte offsets (swizzled group addressing)
  const int sw = l32 & 7;
  int aK[4], aV[4];
#pragma unroll
  for (int dc = 0; dc < 4; ++dc)
    aK[dc] = (wk * 32 + l32) * 128 + (((dc * 2 + h) ^ sw) << 4);
#pragma unroll
  for (int kc = 0; kc < 2; ++kc) {
    aV[kc * 2 + 0] = 16384 + l32 * 128 + (((wk * 4 + kc * 2 + h) ^ sw) << 4);
    aV[kc * 2 + 1] = 16384 + (32 + l32) * 128 + (((wk * 4 + kc * 2 + h) ^ sw) << 4);
  }

  // DMA one 64-key stage (8KB K + 8KB Vt) into buffer nb; 4 instrs/wave
  auto stage = [&](int nxt, int nb) {
    const uint16_t* ks = Kb + (size_t)nxt * 4096 + wave * 1024 + lane * 8;
    const uint16_t* vs = Vtb + (size_t)nxt * 4096 + wave * 1024 + lane * 8;
    char* kd = (char*)sm + nb * 8192 + wave * 2048;
    char* vd = (char*)sm + 16384 + nb * 8192 + wave * 2048;
    gld16(ks, kd);
    gld16(ks + 512, kd + 1024);
    gld16(vs, vd);
    gld16(vs + 512, vd + 1024);
  };
  stage(0, 0);

  f32x16 acc00{}, acc01{}, acc10{}, acc11{};
  float rsum0 = 0.0f, rsum1 = 0.0f;

  auto body = [&](int s, int cb) {
    __syncthreads();               // buffer cb ready; buffer cb^1 free
    if (s + 1 < NSTG) stage(s + 1, cb ^ 1);
    const char* smc = (const char*)sm;
    // S^T = K*Q^T, both tiles share ka
    f32x16 sc0{}, sc1{};
#pragma unroll
    for (int dc = 0; dc < 4; ++dc) {
      bf16x8 ka = *(const bf16x8*)(smc + cb * 8192 + aK[dc]);
      sc0 = __builtin_amdgcn_mfma_f32_32x32x16_bf16(ka, qf[0][dc], sc0, 0, 0, 0);
      sc1 = __builtin_amdgcn_mfma_f32_32x32x16_bf16(ka, qf[1][dc], sc1, 0, 0, 0);
    }
    // p = exp2(s); pack pairs; accumulate rowsum in VALU (all regs share q=l32)
    unsigned w0[8], w1[8];
#pragma unroll
    for (int j = 0; j < 8; ++j) {
      float a0 = __builtin_amdgcn_exp2f(sc0[2 * j]);
      float a1 = __builtin_amdgcn_exp2f(sc0[2 * j + 1]);
      float b0 = __builtin_amdgcn_exp2f(sc1[2 * j]);
      float b1 = __builtin_amdgcn_exp2f(sc1[2 * j + 1]);
      rsum0 += a0 + a1;
      rsum1 += b0 + b1;
      w0[j] = cvt_pk(a0, a1);
      w1[j] = cvt_pk(b0, b1);
    }
    // C->A relayout per tile
    asm("v_permlane32_swap_b32 %0, %1" : "+v"(w0[0]), "+v"(w0[2]));
    asm("v_permlane32_swap_b32 %0, %1" : "+v"(w0[1]), "+v"(w0[3]));
    asm("v_permlane32_swap_b32 %0, %1" : "+v"(w0[4]), "+v"(w0[6]));
    asm("v_permlane32_swap_b32 %0, %1" : "+v"(w0[5]), "+v"(w0[7]));
    asm("v_permlane32_swap_b32 %0, %1" : "+v"(w1[0]), "+v"(w1[2]));
    asm("v_permlane32_swap_b32 %0, %1" : "+v"(w1[1]), "+v"(w1[3]));
    asm("v_permlane32_swap_b32 %0, %1" : "+v"(w1[4]), "+v"(w1[6]));
    asm("v_permlane32_swap_b32 %0, %1" : "+v"(w1[5]), "+v"(w1[7]));
    uint4 u00 = {w0[0], w0[1], w0[2], w0[3]};
    uint4 u01 = {w0[4], w0[5], w0[6], w0[7]};
    uint4 u10 = {w1[0], w1[1], w1[2], w1[3]};
    uint4 u11 = {w1[4], w1[5], w1[6], w1[7]};
    bf16x8 pa00 = __builtin_bit_cast(bf16x8, u00);  // tile0 keys 0..15
    bf16x8 pa01 = __builtin_bit_cast(bf16x8, u01);  // tile0 keys 16..31
    bf16x8 pa10 = __builtin_bit_cast(bf16x8, u10);
    bf16x8 pa11 = __builtin_bit_cast(bf16x8, u11);
    // O += P*V ; V reads shared by both tiles
    bf16x8 v00 = *(const bf16x8*)(smc + cb * 8192 + aV[0]);
    bf16x8 v01 = *(const bf16x8*)(smc + cb * 8192 + aV[1]);
    bf16x8 v10 = *(const bf16x8*)(smc + cb * 8192 + aV[2]);
    bf16x8 v11 = *(const bf16x8*)(smc + cb * 8192 + aV[3]);
    acc00 = __builtin_amdgcn_mfma_f32_32x32x16_bf16(pa00, v00, acc00, 0, 0, 0);
    acc01 = __builtin_amdgcn_mfma_f32_32x32x16_bf16(pa00, v01, acc01, 0, 0, 0);
    acc10 = __builtin_amdgcn_mfma_f32_32x32x16_bf16(pa10, v00, acc10, 0, 0, 0);
    acc11 = __builtin_amdgcn_mfma_f32_32x32x16_bf16(pa10, v01, acc11, 0, 0, 0);
    acc00 = __builtin_amdgcn_mfma_f32_32x32x16_bf16(pa01, v10, acc00, 0, 0, 0);
    acc01 = __builtin_amdgcn_mfma_f32_32x32x16_bf16(pa01, v11, acc01, 0, 0, 0);
    acc10 = __builtin_amdgcn_mfma_f32_32x32x16_bf16(pa11, v10, acc10, 0, 0, 0);
    acc11 = __builtin_amdgcn_mfma_f32_32x32x16_bf16(pa11, v11, acc11, 0, 0, 0);
  };
  for (int it = 0; it < NSTG; it += 2) { body(it, 0); body(it + 1, 1); }

  // ---- epilogue: per tile, combine wk halves via LDS, normalize, store ----
  rsum0 += __shfl_xor(rsum0, 32, 64);
  rsum1 += __shfl_xor(rsum1, 32, 64);
  float* exch = (float*)sm;
  const int ebase = wq * (33 * 64);
#pragma unroll
  for (int t = 0; t < 2; ++t) {
    const f32x16& a0 = t ? acc10 : acc00;
    const f32x16& a1 = t ? acc11 : acc01;
    const float rsum = t ? rsum1 : rsum0;
    __syncthreads();
    if (wk == 1) {
#pragma unroll
      for (int r = 0; r < 16; ++r) {
        exch[ebase + r * 64 + lane]        = a0[r];
        exch[ebase + (16 + r) * 64 + lane] = a1[r];
      }
      exch[ebase + 32 * 64 + lane] = rsum;
    }
    __syncthreads();
    if (wk == 0) {
      const float rt  = rsum + exch[ebase + 32 * 64 + lane];
      const float inv = __builtin_amdgcn_rcpf(rt);   // inv for q=l32
      float* Ob = Og + ((size_t)batch * S_LEN + q0 + t * 64 + wq * 32) * 64;
#pragma unroll
      for (int r = 0; r < 16; ++r) {
        float o0 = a0[r] + exch[ebase + r * 64 + lane];
        float o1 = a1[r] + exch[ebase + (16 + r) * 64 + lane];
        const int qrl = (r & 3) + ((r >> 2) << 3) + (h << 2);  // C row -> q
        const float iv = __shfl(inv, qrl, 64);                 // lane qrl: q=qrl
        float* op = Ob + (size_t)qrl * 64 + l32;
        op[0]  = o0 * iv;
        op[32] = o1 * iv;
      }
    }
  }
}

extern "C" void kernel_launch(void* const* d_in, const int* in_sizes, int n_in,
                              void* d_out, int out_size, void* d_ws, size_t ws_size,
                              hipStream_t stream) {
  const float* Q = (const float*)d_in[0];
  const float* K = (const float*)d_in[1];
  const float* V = (const float*)d_in[2];
  float* O = (float*)d_out;
  uint16_t* Kw = (uint16_t*)d_ws;
  uint16_t* Vw = Kw + (size_t)16 * S_LEN * HD;   // 8.39 MB each, 16.8 MB total
  prep<<<dim3(3072), dim3(256), 0, stream>>>(K, V, Kw, Vw);
  attn_fwd<<<dim3(512), dim3(256), 0, stream>>>(Q, O, Kw, Vw);
}